// Round 3
// baseline (157.291 us; speedup 1.0000x reference)
//
#include <hip/hip_runtime.h>

// RelationAwareDiscriminator:
//   out[b,u,v] = sigmoid( sum_{d,e} UE[u,d] * R[r[b],d,e] * VE[v,e] )
// Dedup: out[b] depends on b only via r[b] (64 distinct relations).
// R3: two-phase via ws. Kernel A computes T = UE.R once per (rel,u-tile).
// Kernel B computes 64x64 sigmoid tiles and replicates to matching b's with
// fine granularity (4096 blocks) so the mc-imbalance tail is schedulable.

#define BATCH 512
#define DIM   128
#define NRELS 64
#define NTHR  256

typedef float floatx4 __attribute__((ext_vector_type(4)));

// ---------------- Kernel A: T[rel][u][e] = sum_d UE[u,d] * R[rel][d,e]
__global__ __launch_bounds__(NTHR, 4)
void rad_phaseA_kernel(const int* __restrict__ u_idx,
                       const float* __restrict__ nodes,
                       const float* __restrict__ rels,
                       float* __restrict__ T_ws)   // [64][512][128]
{
    const int rel = (int)blockIdx.x >> 3;
    const int ut0 = ((int)blockIdx.x & 7) * 64;

    __shared__ __align__(16) float UEsT[DIM * 64];  // [d][u] 32 KB
    __shared__ __align__(16) float Rs[16 * DIM];    // [dd][e] 8 KB

    const int t  = (int)threadIdx.x;
    const int tu = t >> 4;   // 0..15 (u group of 4)
    const int tx = t & 15;   // 0..15 (e group)

    // Gather u-embedding rows, store transposed [d][u].
    for (int i = t; i < 64 * (DIM / 4); i += NTHR) {
        const int row = i & 63;
        const int dc  = i >> 6; // 0..31
        const float4 val = *reinterpret_cast<const float4*>(
            nodes + (size_t)u_idx[ut0 + row] * DIM + dc * 4);
        UEsT[(dc * 4 + 0) * 64 + row] = val.x;
        UEsT[(dc * 4 + 1) * 64 + row] = val.y;
        UEsT[(dc * 4 + 2) * 64 + row] = val.z;
        UEsT[(dc * 4 + 3) * 64 + row] = val.w;
    }

    float accA[4][8];
    #pragma unroll
    for (int i = 0; i < 4; ++i)
        #pragma unroll
        for (int j = 0; j < 8; ++j) accA[i][j] = 0.f;

    const float* Rbase = rels + (size_t)rel * DIM * DIM;
    for (int dch = 0; dch < DIM / 16; ++dch) {
        __syncthreads();
        for (int i = t; i < 16 * (DIM / 4); i += NTHR) {
            const int rr = i >> 5;  // 0..15
            const int cc = i & 31;  // 0..31
            *reinterpret_cast<float4*>(Rs + rr * DIM + cc * 4) =
                *reinterpret_cast<const float4*>(
                    Rbase + (size_t)(dch * 16 + rr) * DIM + cc * 4);
        }
        __syncthreads();
        #pragma unroll
        for (int dd = 0; dd < 16; ++dd) {
            const int d = dch * 16 + dd;
            const float4 a  = *reinterpret_cast<const float4*>(UEsT + d * 64 + tu * 4);
            const float4 b0 = *reinterpret_cast<const float4*>(Rs + dd * DIM + tx * 4);
            const float4 b1 = *reinterpret_cast<const float4*>(Rs + dd * DIM + 64 + tx * 4);
            const float av[4] = {a.x, a.y, a.z, a.w};
            const float bv[8] = {b0.x, b0.y, b0.z, b0.w, b1.x, b1.y, b1.z, b1.w};
            #pragma unroll
            for (int i = 0; i < 4; ++i)
                #pragma unroll
                for (int j = 0; j < 8; ++j)
                    accA[i][j] = fmaf(av[i], bv[j], accA[i][j]);
        }
    }

    // Store T rows: thread (tu,tx) owns u = ut0+tu*4+i, e in {tx*4.., 64+tx*4..}
    #pragma unroll
    for (int i = 0; i < 4; ++i) {
        float* rowp = T_ws + ((size_t)rel * BATCH + ut0 + tu * 4 + i) * DIM;
        *reinterpret_cast<float4*>(rowp + tx * 4) =
            make_float4(accA[i][0], accA[i][1], accA[i][2], accA[i][3]);
        *reinterpret_cast<float4*>(rowp + 64 + tx * 4) =
            make_float4(accA[i][4], accA[i][5], accA[i][6], accA[i][7]);
    }
}

// ---------------- Kernel B: 64x64 sigmoid tile + replicate to matching b's
__global__ __launch_bounds__(NTHR, 2)
void rad_phaseB_kernel(const int* __restrict__ v_idx,
                       const int* __restrict__ r_idx,
                       const float* __restrict__ nodes,
                       const float* __restrict__ T_ws,  // [64][512][128]
                       float* __restrict__ out)         // [512][512][512]
{
    // grid: 64 rels x 8 u-tiles x 8 v-chunks = 4096
    const int bid = (int)blockIdx.x;
    const int rel = bid >> 6;
    const int ut0 = ((bid >> 3) & 7) * 64;
    const int vt0 = (bid & 7) * 64;

    __shared__ int s_match[BATCH];
    __shared__ int s_mc;
    __shared__ __align__(16) float TsT[DIM * 64];   // [e][u] 32 KB
    __shared__ __align__(16) float VEsT[DIM * 64];  // [e][v] 32 KB

    const int t  = (int)threadIdx.x;
    const int tu = t >> 4;   // 0..15
    const int tx = t & 15;   // 0..15

    if (t == 0) s_mc = 0;
    __syncthreads();
    for (int i = t; i < BATCH; i += NTHR) {
        if (r_idx[i] == rel) {
            int p = atomicAdd(&s_mc, 1);
            s_match[p] = i;
        }
    }
    __syncthreads();
    const int mc = s_mc;
    if (mc == 0) return;

    // Load T tile transposed [e][u] (ws is L3-resident).
    for (int i = t; i < 64 * (DIM / 4); i += NTHR) {
        const int row = i & 63;
        const int ec  = i >> 6; // 0..31
        const float4 val = *reinterpret_cast<const float4*>(
            T_ws + ((size_t)rel * BATCH + ut0 + row) * DIM + ec * 4);
        TsT[(ec * 4 + 0) * 64 + row] = val.x;
        TsT[(ec * 4 + 1) * 64 + row] = val.y;
        TsT[(ec * 4 + 2) * 64 + row] = val.z;
        TsT[(ec * 4 + 3) * 64 + row] = val.w;
    }
    // Gather v-embedding rows transposed [e][v].
    for (int i = t; i < 64 * (DIM / 4); i += NTHR) {
        const int row = i & 63;
        const int ec  = i >> 6;
        const float4 val = *reinterpret_cast<const float4*>(
            nodes + (size_t)v_idx[vt0 + row] * DIM + ec * 4);
        VEsT[(ec * 4 + 0) * 64 + row] = val.x;
        VEsT[(ec * 4 + 1) * 64 + row] = val.y;
        VEsT[(ec * 4 + 2) * 64 + row] = val.z;
        VEsT[(ec * 4 + 3) * 64 + row] = val.w;
    }
    __syncthreads();

    float acc[4][4];
    #pragma unroll
    for (int i = 0; i < 4; ++i)
        #pragma unroll
        for (int j = 0; j < 4; ++j) acc[i][j] = 0.f;

    #pragma unroll 8
    for (int e = 0; e < DIM; ++e) {
        const float4 a = *reinterpret_cast<const float4*>(TsT  + e * 64 + tu * 4);
        const float4 b = *reinterpret_cast<const float4*>(VEsT + e * 64 + tx * 4);
        const float av[4] = {a.x, a.y, a.z, a.w};
        const float bv[4] = {b.x, b.y, b.z, b.w};
        #pragma unroll
        for (int i = 0; i < 4; ++i)
            #pragma unroll
            for (int j = 0; j < 4; ++j)
                acc[i][j] = fmaf(av[i], bv[j], acc[i][j]);
    }

    floatx4 sg[4];
    #pragma unroll
    for (int i = 0; i < 4; ++i) {
        sg[i].x = 1.f / (1.f + __expf(-acc[i][0]));
        sg[i].y = 1.f / (1.f + __expf(-acc[i][1]));
        sg[i].z = 1.f / (1.f + __expf(-acc[i][2]));
        sg[i].w = 1.f / (1.f + __expf(-acc[i][3]));
    }

    for (int m = 0; m < mc; ++m) {
        const int bb = s_match[m];
        float* obase = out + (size_t)bb * BATCH * BATCH;
        #pragma unroll
        for (int i = 0; i < 4; ++i) {
            floatx4* dst = reinterpret_cast<floatx4*>(
                obase + (size_t)(ut0 + tu * 4 + i) * BATCH + vt0 + tx * 4);
            __builtin_nontemporal_store(sg[i], dst);
        }
    }
}

// ---------------- Fallback: proven single-kernel version (R2, 144.5 us)
__global__ __launch_bounds__(NTHR, 2)
void rad_fused_kernel(const int* __restrict__ u_idx,
                      const int* __restrict__ v_idx,
                      const int* __restrict__ r_idx,
                      const float* __restrict__ nodes,
                      const float* __restrict__ rels,
                      float* __restrict__ out)
{
    const int rel = (int)blockIdx.x >> 3;
    const int ut0 = ((int)blockIdx.x & 7) * 64;

    __shared__ int s_match[BATCH];
    __shared__ int s_mc;
    __shared__ __align__(16) float s_TsT[DIM * 64];
    __shared__ __align__(16) float s_buf[DIM * 64 + 16 * DIM];

    const int t  = (int)threadIdx.x;
    const int tu = t >> 4;
    const int tx = t & 15;

    if (t == 0) s_mc = 0;
    __syncthreads();
    for (int i = t; i < BATCH; i += NTHR) {
        if (r_idx[i] == rel) {
            int p = atomicAdd(&s_mc, 1);
            s_match[p] = i;
        }
    }

    float* UEsT = s_buf;
    float* Rs   = s_buf + DIM * 64;

    for (int i = t; i < 64 * (DIM / 4); i += NTHR) {
        const int row = i & 63;
        const int dc  = i >> 6;
        const float4 val = *reinterpret_cast<const float4*>(
            nodes + (size_t)u_idx[ut0 + row] * DIM + dc * 4);
        UEsT[(dc * 4 + 0) * 64 + row] = val.x;
        UEsT[(dc * 4 + 1) * 64 + row] = val.y;
        UEsT[(dc * 4 + 2) * 64 + row] = val.z;
        UEsT[(dc * 4 + 3) * 64 + row] = val.w;
    }
    __syncthreads();
    const int mc = s_mc;
    if (mc == 0) return;

    float accA[4][8];
    #pragma unroll
    for (int i = 0; i < 4; ++i)
        #pragma unroll
        for (int j = 0; j < 8; ++j) accA[i][j] = 0.f;

    const float* Rbase = rels + (size_t)rel * DIM * DIM;
    for (int dch = 0; dch < DIM / 16; ++dch) {
        for (int i = t; i < 16 * (DIM / 4); i += NTHR) {
            const int rr = i >> 5;
            const int cc = i & 31;
            *reinterpret_cast<float4*>(Rs + rr * DIM + cc * 4) =
                *reinterpret_cast<const float4*>(
                    Rbase + (size_t)(dch * 16 + rr) * DIM + cc * 4);
        }
        __syncthreads();
        #pragma unroll
        for (int dd = 0; dd < 16; ++dd) {
            const int d = dch * 16 + dd;
            const float4 a  = *reinterpret_cast<const float4*>(UEsT + d * 64 + tu * 4);
            const float4 b0 = *reinterpret_cast<const float4*>(Rs + dd * DIM + tx * 4);
            const float4 b1 = *reinterpret_cast<const float4*>(Rs + dd * DIM + 64 + tx * 4);
            const float av[4] = {a.x, a.y, a.z, a.w};
            const float bv[8] = {b0.x, b0.y, b0.z, b0.w, b1.x, b1.y, b1.z, b1.w};
            #pragma unroll
            for (int i = 0; i < 4; ++i)
                #pragma unroll
                for (int j = 0; j < 8; ++j)
                    accA[i][j] = fmaf(av[i], bv[j], accA[i][j]);
        }
        __syncthreads();
    }

    #pragma unroll
    for (int j = 0; j < 8; ++j) {
        const int e = (j < 4) ? (tx * 4 + j) : (64 + tx * 4 + (j - 4));
        #pragma unroll
        for (int i = 0; i < 4; ++i)
            s_TsT[e * 64 + tu * 4 + i] = accA[i][j];
    }

    float* VEsT = s_buf;
    for (int vt = 0; vt < BATCH / 64; ++vt) {
        __syncthreads();
        for (int i = t; i < 64 * (DIM / 4); i += NTHR) {
            const int row = i & 63;
            const int ec  = i >> 6;
            const float4 val = *reinterpret_cast<const float4*>(
                nodes + (size_t)v_idx[vt * 64 + row] * DIM + ec * 4);
            VEsT[(ec * 4 + 0) * 64 + row] = val.x;
            VEsT[(ec * 4 + 1) * 64 + row] = val.y;
            VEsT[(ec * 4 + 2) * 64 + row] = val.z;
            VEsT[(ec * 4 + 3) * 64 + row] = val.w;
        }
        __syncthreads();

        float acc[4][4];
        #pragma unroll
        for (int i = 0; i < 4; ++i)
            #pragma unroll
            for (int j = 0; j < 4; ++j) acc[i][j] = 0.f;

        #pragma unroll 8
        for (int e = 0; e < DIM; ++e) {
            const float4 a = *reinterpret_cast<const float4*>(s_TsT + e * 64 + tu * 4);
            const float4 b = *reinterpret_cast<const float4*>(VEsT  + e * 64 + tx * 4);
            const float av[4] = {a.x, a.y, a.z, a.w};
            const float bv[4] = {b.x, b.y, b.z, b.w};
            #pragma unroll
            for (int i = 0; i < 4; ++i)
                #pragma unroll
                for (int j = 0; j < 4; ++j)
                    acc[i][j] = fmaf(av[i], bv[j], acc[i][j]);
        }

        floatx4 sg[4];
        #pragma unroll
        for (int i = 0; i < 4; ++i) {
            sg[i].x = 1.f / (1.f + __expf(-acc[i][0]));
            sg[i].y = 1.f / (1.f + __expf(-acc[i][1]));
            sg[i].z = 1.f / (1.f + __expf(-acc[i][2]));
            sg[i].w = 1.f / (1.f + __expf(-acc[i][3]));
        }

        for (int m = 0; m < mc; ++m) {
            const int bb = s_match[m];
            float* obase = out + (size_t)bb * BATCH * BATCH;
            #pragma unroll
            for (int i = 0; i < 4; ++i) {
                floatx4* dst = reinterpret_cast<floatx4*>(
                    obase + (size_t)(ut0 + tu * 4 + i) * BATCH + vt * 64 + tx * 4);
                __builtin_nontemporal_store(sg[i], dst);
            }
        }
    }
}

extern "C" void kernel_launch(void* const* d_in, const int* in_sizes, int n_in,
                              void* d_out, int out_size, void* d_ws, size_t ws_size,
                              hipStream_t stream) {
    const int*   u_idx = (const int*)d_in[0];
    const int*   v_idx = (const int*)d_in[1];
    const int*   r_idx = (const int*)d_in[2];
    const float* nodes = (const float*)d_in[3];
    const float* rels  = (const float*)d_in[4];
    float* out = (float*)d_out;

    const size_t t_bytes = (size_t)NRELS * BATCH * DIM * sizeof(float); // 16.78 MB
    if (ws_size >= t_bytes) {
        float* T_ws = (float*)d_ws;
        rad_phaseA_kernel<<<dim3(NRELS * 8), dim3(NTHR), 0, stream>>>(
            u_idx, nodes, rels, T_ws);
        rad_phaseB_kernel<<<dim3(NRELS * 8 * 8), dim3(NTHR), 0, stream>>>(
            v_idx, r_idx, nodes, T_ws, out);
    } else {
        rad_fused_kernel<<<dim3(NRELS * 8), dim3(NTHR), 0, stream>>>(
            u_idx, v_idx, r_idx, nodes, rels, out);
    }
}